// Round 5
// baseline (68.205 us; speedup 1.0000x reference)
//
#include <hip/hip_runtime.h>

// GraphProjection on MI355X (gfx950).
// x:(8,512,64,64) f32, anchor/sigma:(128,512) f32.
// d_out = nodes (8,512,128) ++ soft_assign (8,128,256).
//
// gp_prep:   rs=1/sigma, ars=anchor/sigma table [g][c][16].
// gp_logits: block = (b, y); lane = full-width pixel x so every x load is one
//            256-B contiguous row; wave = c-eighth; per-lane gx anchor access
//            via vector loads (L2-resident table); softmax combine via one LDS
//            scratch + barrier. Writes soft_assign.
// gp_accum:  UNCHANGED from round 3 (A/B discipline).
// gp_final:  UNCHANGED.
// (Round 4 bench was an infra failure; this is an identical resubmit.)

#define NCH 512

typedef __attribute__((address_space(3))) void lds_void_t;
typedef const __attribute__((address_space(1))) void gbl_void_t;

__device__ __forceinline__ void gload_lds16(const float* g, float* l) {
  __builtin_amdgcn_global_load_lds((gbl_void_t*)g, (lds_void_t*)l, 16, 0, 0);
}

// ---------------------------------------------------------------- prep
__global__ __launch_bounds__(512, 2)
void gp_prep(const float* __restrict__ anchor,
             const float* __restrict__ sigma,
             float* __restrict__ ws_anc) {   // [16][512][16]
  const int g = blockIdx.x;    // 0..15
  const int c = threadIdx.x;   // 0..511
  float vals[16];
#pragma unroll
  for (int k = 0; k < 8; ++k) {
    float a = anchor[((g << 3) + k) * NCH + c];
    float s = sigma [((g << 3) + k) * NCH + c];
    float r = 1.0f / s;
    vals[k]     = r;
    vals[k + 8] = a * r;
  }
  float4* dst = (float4*)(ws_anc + (((size_t)g * NCH + c) << 4));
#pragma unroll
  for (int q = 0; q < 4; ++q) dst[q] = ((float4*)vals)[q];
}

// ---------------------------------------------------------------- pass 1
__global__ __launch_bounds__(512, 2)
void gp_logits(const float* __restrict__ x,
               const float* __restrict__ ws_anc,
               float* __restrict__ soft_out) {
  __shared__ float sc[8 * 64 * 8];   // [wave][px][k] 16 KB
  const int tid = threadIdx.x;
  const int bid = blockIdx.x;        // = b*64 + y
  const int y  = bid & 63;
  const int b  = bid >> 6;
  const int gy = y >> 4;
  const int w  = __builtin_amdgcn_readfirstlane(tid >> 6);  // c-eighth
  const int lane = tid & 63;         // = pixel x (full width)
  const int gx = lane >> 4;
  const int g  = (gy << 2) + gx;

  // x row pointer: 64 lanes cover one full 256-B row per channel
  const float* xp = x + (size_t)b * (NCH * 4096)
                      + (size_t)(w << 6) * 4096 + y * 64 + lane;
  // per-lane anchor table slice (16-lane broadcast within each gx group)
  const float4* ap = (const float4*)(ws_anc + (((size_t)g * NCH + (w << 6)) << 4));

  float sq[8];
#pragma unroll
  for (int k = 0; k < 8; ++k) sq[k] = 0.0f;

#pragma unroll 4
  for (int cc = 0; cc < 64; ++cc) {
    float xv = xp[(size_t)cc * 4096];
    float4 r0 = ap[(cc << 2) + 0];
    float4 r1 = ap[(cc << 2) + 1];
    float4 a0 = ap[(cc << 2) + 2];
    float4 a1 = ap[(cc << 2) + 3];
    float t;
    t = fmaf(xv, r0.x, -a0.x); sq[0] = fmaf(t, t, sq[0]);
    t = fmaf(xv, r0.y, -a0.y); sq[1] = fmaf(t, t, sq[1]);
    t = fmaf(xv, r0.z, -a0.z); sq[2] = fmaf(t, t, sq[2]);
    t = fmaf(xv, r0.w, -a0.w); sq[3] = fmaf(t, t, sq[3]);
    t = fmaf(xv, r1.x, -a1.x); sq[4] = fmaf(t, t, sq[4]);
    t = fmaf(xv, r1.y, -a1.y); sq[5] = fmaf(t, t, sq[5]);
    t = fmaf(xv, r1.z, -a1.z); sq[6] = fmaf(t, t, sq[6]);
    t = fmaf(xv, r1.w, -a1.w); sq[7] = fmaf(t, t, sq[7]);
  }

  const int sbase = ((w << 6) + lane) << 3;
  *(float4*)&sc[sbase]     = make_float4(sq[0], sq[1], sq[2], sq[3]);
  *(float4*)&sc[sbase + 4] = make_float4(sq[4], sq[5], sq[6], sq[7]);
  __syncthreads();

  // combine 8 c-partials + softmax over nodes; thread = (px, k)
  {
    const int px = tid >> 3, k = tid & 7;
    float acc = 0.0f;
#pragma unroll
    for (int w2 = 0; w2 < 8; ++w2) acc += sc[(w2 << 9) + tid];  // conflict-free
    float l = -0.5f * acc;
    float mx = l;
    mx = fmaxf(mx, __shfl_xor(mx, 1, 64));
    mx = fmaxf(mx, __shfl_xor(mx, 2, 64));
    mx = fmaxf(mx, __shfl_xor(mx, 4, 64));
    float e = __expf(l - mx);
    float es = e;
    es += __shfl_xor(es, 1, 64);
    es += __shfl_xor(es, 2, 64);
    es += __shfl_xor(es, 4, 64);
    const int og = (gy << 2) + (px >> 4);
    soft_out[(size_t)((b << 7) + (og << 3) + k) * 256 +
             ((y & 15) << 4) + (px & 15)] = e / es;
  }
}

// ---------------------------------------------------------------- pass 2
__global__ __launch_bounds__(512, 2)
void gp_accum(const float* __restrict__ x,
              const float* __restrict__ soft_in,
              float* __restrict__ ws_s1,
              int plog) {
  __shared__ float chunk[2][NCH * 16];   // 64 KB, quad-swizzled rows
  __shared__ float soft_lds[256 * 8];    // [pxp][k] (sized for plog=0)
  const int tid = threadIdx.x;
  const int bid = blockIdx.x;            // gx*(32<<plog) + (b*(4<<plog)+gy*(1<<plog)+part)
  const int parts = 1 << plog;
  const int gx = bid >> (5 + plog);
  const int r  = bid & ((32 << plog) - 1);
  const int part = r & (parts - 1);
  const int gy = (r >> plog) & 3;
  const int b  = r >> (plog + 2);
  const int g  = (gy << 2) + gx;
  const int nrows = 16 >> plog;
  const int npx   = nrows << 4;
  const int y0 = (gy << 4) + part * nrows;
  const int x0 = gx << 4;
  const float* xb = x + (size_t)b * (NCH * 4096);

  // soft -> LDS [pxp][k]
  for (int i = tid; i < npx * 8; i += 512) {
    int k   = i >> (8 - plog);
    int pxp = i & (npx - 1);
    soft_lds[(pxp << 3) + k] =
        soft_in[(size_t)((b << 7) + (g << 3) + k) * 256 + part * npx + pxp];
  }

  auto stage = [&](int buf, int row) {
#pragma unroll
    for (int it = 0; it < 4; ++it) {
      int flat = it * 512 + tid;
      int ci   = flat >> 2;
      int qd   = flat & 3;
      int qs   = qd ^ ((ci >> 1) & 3);
      const float* src = xb + (size_t)ci * 4096 + (y0 + row) * 64 + x0 + (qs << 2);
      gload_lds16(src, &chunk[buf][flat << 2]);
    }
  };

  float S1[8];
#pragma unroll
  for (int k = 0; k < 8; ++k) S1[k] = 0.0f;

  stage(0, 0);
  asm volatile("s_waitcnt lgkmcnt(0)" ::: "memory");  // soft_lds writes drained

  const int csw = (tid >> 1) & 3;
  for (int rr = 0; rr < nrows; ++rr) {
    const int cur = rr & 1;
    if (rr < nrows - 1) {
      stage(cur ^ 1, rr + 1);                       // next row in flight
      asm volatile("s_waitcnt vmcnt(4)" ::: "memory");  // current row landed
    } else {
      asm volatile("s_waitcnt vmcnt(0)" ::: "memory");
    }
    asm volatile("s_barrier" ::: "memory");          // raw: no vmcnt(0) drain

    const float* ch = &chunk[cur][tid << 4];
#pragma unroll
    for (int qd = 0; qd < 4; ++qd) {
      float4 xv = *(const float4*)(ch + ((qd ^ csw) << 2));
#pragma unroll
      for (int j = 0; j < 4; ++j) {
        float xvj = (j == 0) ? xv.x : (j == 1) ? xv.y : (j == 2) ? xv.z : xv.w;
        const float* sp = &soft_lds[((rr << 4) + (qd << 2) + j) << 3];
        float4 s0 = *(const float4*)sp;
        float4 s1 = *(const float4*)(sp + 4);
        S1[0] = fmaf(xvj, s0.x, S1[0]);
        S1[1] = fmaf(xvj, s0.y, S1[1]);
        S1[2] = fmaf(xvj, s0.z, S1[2]);
        S1[3] = fmaf(xvj, s0.w, S1[3]);
        S1[4] = fmaf(xvj, s1.x, S1[4]);
        S1[5] = fmaf(xvj, s1.y, S1[5]);
        S1[6] = fmaf(xvj, s1.z, S1[6]);
        S1[7] = fmaf(xvj, s1.w, S1[7]);
      }
    }
    asm volatile("s_barrier" ::: "memory");  // reads done before buf reuse
  }

  const int bg = (b << 4) + g;
  float* wp = ws_s1 + ((size_t)(bg * parts + part) << 3) * NCH + tid;
#pragma unroll
  for (int k = 0; k < 8; ++k) wp[k * NCH] = S1[k];
}

// ---------------------------------------------------------------- finalize
__global__ __launch_bounds__(512, 4)
void gp_final(const float* __restrict__ anchor,
              const float* __restrict__ sigma,
              const float* __restrict__ soft_out,
              const float* __restrict__ ws_s1,
              float* __restrict__ nodes_out,
              int parts) {
  const int bg = blockIdx.x;   // b*16+g
  const int b  = bg >> 4, g = bg & 15;
  const int tid = threadIdx.x; // channel c
  __shared__ float sS0[8];
  __shared__ float red[8 * 8];
  __shared__ float invn[8];

  if (tid < 256) {
    int k = tid >> 5, sl = tid & 31;
    const float* sp = soft_out + (size_t)((b << 7) + (g << 3) + k) * 256 + (sl << 3);
    float4 a0 = *(const float4*)sp;
    float4 a1 = *(const float4*)(sp + 4);
    float v = a0.x + a0.y + a0.z + a0.w + a1.x + a1.y + a1.z + a1.w;
    v += __shfl_xor(v, 1, 64);
    v += __shfl_xor(v, 2, 64);
    v += __shfl_xor(v, 4, 64);
    v += __shfl_xor(v, 8, 64);
    v += __shfl_xor(v, 16, 64);
    if (sl == 0) sS0[k] = v;
  }
  __syncthreads();

  float S1[8];
#pragma unroll
  for (int k = 0; k < 8; ++k) S1[k] = 0.0f;
  for (int pt = 0; pt < parts; ++pt) {
    const float* wp = ws_s1 + ((size_t)(bg * parts + pt) << 3) * NCH + tid;
#pragma unroll
    for (int k = 0; k < 8; ++k) S1[k] += wp[k * NCH];
  }

  float v[8];
#pragma unroll
  for (int k = 0; k < 8; ++k) {
    float s  = sigma [((g << 3) + k) * NCH + tid];
    float a  = anchor[((g << 3) + k) * NCH + tid];
    float rs = 1.0f / s;
    float S0 = sS0[k];
    float nd = rs * S1[k] - (a * rs) * S0;
    v[k] = nd / (S0 + 1e-9f);
  }

  const int wv = tid >> 6, lane = tid & 63;
#pragma unroll
  for (int k = 0; k < 8; ++k) {
    float s = v[k] * v[k];
    s += __shfl_xor(s, 1, 64);
    s += __shfl_xor(s, 2, 64);
    s += __shfl_xor(s, 4, 64);
    s += __shfl_xor(s, 8, 64);
    s += __shfl_xor(s, 16, 64);
    s += __shfl_xor(s, 32, 64);
    if (lane == 0) red[(wv << 3) + k] = s;
  }
  __syncthreads();
  if (tid < 8) {
    float t2 = 0.0f;
#pragma unroll
    for (int w = 0; w < 8; ++w) t2 += red[(w << 3) + tid];
    invn[tid] = 1.0f / fmaxf(sqrtf(t2), 1e-12f);
  }
  __syncthreads();

  float4 o0 = make_float4(v[0] * invn[0], v[1] * invn[1], v[2] * invn[2], v[3] * invn[3]);
  float4 o1 = make_float4(v[4] * invn[4], v[5] * invn[5], v[6] * invn[6], v[7] * invn[7]);
  float* dst = nodes_out + ((size_t)(b * NCH) + tid) * 128 + (g << 3);
  *(float4*)(dst)     = o0;
  *(float4*)(dst + 4) = o1;
}

extern "C" void kernel_launch(void* const* d_in, const int* in_sizes, int n_in,
                              void* d_out, int out_size, void* d_ws, size_t ws_size,
                              hipStream_t stream) {
  const float* x      = (const float*)d_in[0];
  const float* anchor = (const float*)d_in[1];
  const float* sigma  = (const float*)d_in[2];
  float* out = (float*)d_out;
  float* wsf = (float*)d_ws;

  const size_t n_nodes = 524288;           // 8*512*128
  float* soft_out = out + n_nodes;
  float* ws_anc = wsf;                     // 16*512*16 = 131072 floats
  float* ws_s1  = wsf + 131072;

  int plog;
  if      (ws_size >= (131072 + 4u * 524288) * sizeof(float)) plog = 2;
  else if (ws_size >= (131072 + 2u * 524288) * sizeof(float)) plog = 1;
  else                                                        plog = 0;

  gp_prep  <<<16,           512, 0, stream>>>(anchor, sigma, ws_anc);
  gp_logits<<<512,          512, 0, stream>>>(x, ws_anc, soft_out);
  gp_accum <<<128 << plog,  512, 0, stream>>>(x, soft_out, ws_s1, plog);
  gp_final <<<128,          512, 0, stream>>>(anchor, sigma, soft_out, ws_s1, out,
                                              1 << plog);
}

// Round 6
// 46.270 us; speedup vs baseline: 1.4741x; 1.4741x over previous
//
#include <hip/hip_runtime.h>

// GraphProjection on MI355X (gfx950) — fused single-pass structure.
// x:(8,512,64,64) f32, anchor/sigma:(128,512) f32.
// d_out = nodes (8,512,128) ++ soft_assign (8,128,256).
//
// gp_prep:  rs=1/sigma, ars=anchor/sigma table [g][c][16].
// gp_fused: block = (b, g, half). Per 16-px row: double-buffered
//           global_load_lds staging (counted vmcnt, raw s_barrier — the
//           round-3 gp_accum pipeline that measured near-BW), pass-1 logits
//           (thread=(px,cg), anc quad-swizzled in LDS), scratch-combine +
//           softmax, pass-2 S1 accumulation. x read ONCE. soft_assign kept in
//           LDS, written at kernel end (no global ops inside the vmcnt'd loop).
// gp_final: combine 2 partials, S0 from soft_assign, normalize, transposed store.

#define NCH 512
#define PARTS 2
#define NROWS 8   // rows per block

typedef __attribute__((address_space(3))) void lds_void_t;
typedef const __attribute__((address_space(1))) void gbl_void_t;

__device__ __forceinline__ void gload_lds16(const float* g, float* l) {
  __builtin_amdgcn_global_load_lds((gbl_void_t*)g, (lds_void_t*)l, 16, 0, 0);
}

// ---------------------------------------------------------------- prep
__global__ __launch_bounds__(512, 2)
void gp_prep(const float* __restrict__ anchor,
             const float* __restrict__ sigma,
             float* __restrict__ ws_anc) {   // [16][512][16]
  const int g = blockIdx.x;    // 0..15
  const int c = threadIdx.x;   // 0..511
  float vals[16];
#pragma unroll
  for (int k = 0; k < 8; ++k) {
    float a = anchor[((g << 3) + k) * NCH + c];
    float s = sigma [((g << 3) + k) * NCH + c];
    float r = 1.0f / s;
    vals[k]     = r;       // logical quads: q0=rs[0..3] q1=rs[4..7]
    vals[k + 8] = a * r;   //                q2=ars[0..3] q3=ars[4..7]
  }
  float4* dst = (float4*)(ws_anc + (((size_t)g * NCH + c) << 4));
#pragma unroll
  for (int q = 0; q < 4; ++q) dst[q] = ((float4*)vals)[q];
}

// ---------------------------------------------------------------- fused main
struct SharedFused {
  float anc[NCH * 16];        // 32 KB  [c][16], quad q at pos q^((c>>4)&3)
  float chunk[2][NCH * 16];   // 64 KB  [c][16px], pixel-quad q at pos q^((c>>1)&3)
  float scratch[8 * 16 * 8];  // 4 KB   [wave][px][k]
  float soft[16 * 8];         // 512 B  [px][k] current row
  float soft_all[NROWS * 128];// 4 KB   [row][px][k]
};

__global__ __launch_bounds__(512, 2)
void gp_fused(const float* __restrict__ x,
              const float* __restrict__ ws_anc,
              float* __restrict__ soft_out,
              float* __restrict__ ws_s1) {
  __shared__ SharedFused sh;
  const int tid = threadIdx.x;
  const int bid = blockIdx.x;       // gx*64 + ((b*4+gy)*2 + part)
  const int gx   = bid >> 6;        // gx-siblings share bid%8 -> same XCD
  const int r    = bid & 63;
  const int part = r & 1;
  const int gy   = (r >> 1) & 3;
  const int b    = r >> 3;
  const int g    = (gy << 2) + gx;
  const int y0   = (gy << 4) + part * NROWS;
  const int x0   = gx << 4;
  const float* xb = x + (size_t)b * (NCH * 4096);

  // ---- stage anc table (32 KB): LDS quad (c,p) <- table quad (c, p^sw)
  {
    const float* tb = ws_anc + (size_t)g * (NCH * 16);
#pragma unroll
    for (int it = 0; it < 4; ++it) {
      int qf = it * 512 + tid;          // quad 0..2047
      int c  = qf >> 2;
      int p  = qf & 3;
      int ps = p ^ ((c >> 4) & 3);
      gload_lds16(tb + c * 16 + (ps << 2), &sh.anc[qf << 2]);
    }
  }

  auto stage = [&](int buf, int row) {
#pragma unroll
    for (int it = 0; it < 4; ++it) {
      int qf = it * 512 + tid;
      int ci = qf >> 2;
      int qd = qf & 3;
      int qs = qd ^ ((ci >> 1) & 3);
      gload_lds16(xb + (size_t)ci * 4096 + (y0 + row) * 64 + x0 + (qs << 2),
                  &sh.chunk[buf][qf << 2]);
    }
  };
  stage(0, 0);
  asm volatile("s_waitcnt vmcnt(0) lgkmcnt(0)\ns_barrier" ::: "memory");

  float S1[8];
#pragma unroll
  for (int k = 0; k < 8; ++k) S1[k] = 0.0f;

  const int cg = tid >> 4, px = tid & 15;
  const int wv = tid >> 6, lane = tid & 63;
  const int asw = cg & 3;
  const int pq = px >> 2, pr = px & 3;
  const int csw2 = (tid >> 1) & 3;

  for (int rr = 0; rr < NROWS; ++rr) {
    const int cur = rr & 1;
    if (rr + 1 < NROWS) {
      stage(cur ^ 1, rr + 1);                        // next row in flight
      asm volatile("s_waitcnt vmcnt(4)" ::: "memory");   // current row landed
    } else {
      asm volatile("s_waitcnt vmcnt(0)" ::: "memory");
    }
    asm volatile("s_barrier" ::: "memory");          // B1: chunk[cur] ready

    // ---- pass 1: sq over this thread's 16 channels
    float sq[8];
#pragma unroll
    for (int k = 0; k < 8; ++k) sq[k] = 0.0f;
    {
      const float* ancb = sh.anc + cg * 256;
      const float* chb  = sh.chunk[cur] + (cg << 8);
#pragma unroll
      for (int i = 0; i < 16; ++i) {
        const float* ar = ancb + i * 16;
        float4 rlo = *(const float4*)(ar + ((0 ^ asw) << 2));
        float4 rhi = *(const float4*)(ar + ((1 ^ asw) << 2));
        float4 alo = *(const float4*)(ar + ((2 ^ asw) << 2));
        float4 ahi = *(const float4*)(ar + ((3 ^ asw) << 2));
        float xv = chb[(i << 4) + (((pq ^ ((i >> 1) & 3))) << 2) + pr];
        float t;
        t = fmaf(xv, rlo.x, -alo.x); sq[0] = fmaf(t, t, sq[0]);
        t = fmaf(xv, rlo.y, -alo.y); sq[1] = fmaf(t, t, sq[1]);
        t = fmaf(xv, rlo.z, -alo.z); sq[2] = fmaf(t, t, sq[2]);
        t = fmaf(xv, rlo.w, -alo.w); sq[3] = fmaf(t, t, sq[3]);
        t = fmaf(xv, rhi.x, -ahi.x); sq[4] = fmaf(t, t, sq[4]);
        t = fmaf(xv, rhi.y, -ahi.y); sq[5] = fmaf(t, t, sq[5]);
        t = fmaf(xv, rhi.z, -ahi.z); sq[6] = fmaf(t, t, sq[6]);
        t = fmaf(xv, rhi.w, -ahi.w); sq[7] = fmaf(t, t, sq[7]);
      }
    }
#pragma unroll
    for (int k = 0; k < 8; ++k) {      // combine wave's 4 channel-groups
      sq[k] += __shfl_xor(sq[k], 16, 64);
      sq[k] += __shfl_xor(sq[k], 32, 64);
    }
    if (lane < 16) {                   // lane == px
      *(float4*)&sh.scratch[((wv << 4) + lane) << 3]       =
          make_float4(sq[0], sq[1], sq[2], sq[3]);
      *(float4*)&sh.scratch[(((wv << 4) + lane) << 3) + 4] =
          make_float4(sq[4], sq[5], sq[6], sq[7]);
    }
    asm volatile("s_waitcnt lgkmcnt(0)\ns_barrier" ::: "memory");  // B2

    // ---- combine 8 waves + softmax; thread = (px2, k)
    if (tid < 128) {
      float acc = 0.0f;
#pragma unroll
      for (int w2 = 0; w2 < 8; ++w2) acc += sh.scratch[(w2 << 7) + tid];
      float l = -0.5f * acc;
      float mx = l;
      mx = fmaxf(mx, __shfl_xor(mx, 1, 64));
      mx = fmaxf(mx, __shfl_xor(mx, 2, 64));
      mx = fmaxf(mx, __shfl_xor(mx, 4, 64));
      float e = __expf(l - mx);
      float es = e;
      es += __shfl_xor(es, 1, 64);
      es += __shfl_xor(es, 2, 64);
      es += __shfl_xor(es, 4, 64);
      float sv = e / es;
      sh.soft[tid] = sv;
      sh.soft_all[(rr << 7) + tid] = sv;
    }
    asm volatile("s_waitcnt lgkmcnt(0)\ns_barrier" ::: "memory");  // B3: soft ready

    // ---- pass 2: S1[k] += sum_px chunk[c][px] * soft[px][k]   (c = tid)
    {
      const float* ch = sh.chunk[cur] + (tid << 4);
#pragma unroll
      for (int qd = 0; qd < 4; ++qd) {
        float4 xv = *(const float4*)(ch + ((qd ^ csw2) << 2));
#pragma unroll
        for (int j = 0; j < 4; ++j) {
          float xvj = (j == 0) ? xv.x : (j == 1) ? xv.y : (j == 2) ? xv.z : xv.w;
          const float* sp = &sh.soft[((qd << 2) + j) << 3];
          float4 s0 = *(const float4*)sp;
          float4 s1 = *(const float4*)(sp + 4);
          S1[0] = fmaf(xvj, s0.x, S1[0]);
          S1[1] = fmaf(xvj, s0.y, S1[1]);
          S1[2] = fmaf(xvj, s0.z, S1[2]);
          S1[3] = fmaf(xvj, s0.w, S1[3]);
          S1[4] = fmaf(xvj, s1.x, S1[4]);
          S1[5] = fmaf(xvj, s1.y, S1[5]);
          S1[6] = fmaf(xvj, s1.z, S1[6]);
          S1[7] = fmaf(xvj, s1.w, S1[7]);
        }
      }
    }
    asm volatile("s_barrier" ::: "memory");  // B4: chunk[cur] reads done
  }

  // ---- epilogue: S1 partial (coalesced) + soft_assign from LDS
  const int bg = (b << 4) + g;
  {
    float* wp = ws_s1 + ((size_t)(bg * PARTS + part) << 3) * NCH + tid;
#pragma unroll
    for (int k = 0; k < 8; ++k) wp[k * NCH] = S1[k];
  }
  {
    float* so = soft_out + (size_t)((b << 7) + (g << 3)) * 256 + part * 128;
#pragma unroll
    for (int it = 0; it < 2; ++it) {
      int i   = it * 512 + tid;      // 0..1023 = k*128 + gpx
      int k   = i >> 7;
      int gpx = i & 127;
      so[(size_t)k * 256 + gpx] =
          sh.soft_all[((gpx >> 4) << 7) + ((gpx & 15) << 3) + k];
    }
  }
}

// ---------------------------------------------------------------- finalize
__global__ __launch_bounds__(512, 4)
void gp_final(const float* __restrict__ anchor,
              const float* __restrict__ sigma,
              const float* __restrict__ soft_out,
              const float* __restrict__ ws_s1,
              float* __restrict__ nodes_out) {
  const int bg = blockIdx.x;   // b*16+g
  const int b  = bg >> 4, g = bg & 15;
  const int tid = threadIdx.x; // channel c
  __shared__ float sS0[8];
  __shared__ float red[8 * 8];
  __shared__ float invn[8];

  if (tid < 256) {
    int k = tid >> 5, sl = tid & 31;
    const float* sp = soft_out + (size_t)((b << 7) + (g << 3) + k) * 256 + (sl << 3);
    float4 a0 = *(const float4*)sp;
    float4 a1 = *(const float4*)(sp + 4);
    float v = a0.x + a0.y + a0.z + a0.w + a1.x + a1.y + a1.z + a1.w;
    v += __shfl_xor(v, 1, 64);
    v += __shfl_xor(v, 2, 64);
    v += __shfl_xor(v, 4, 64);
    v += __shfl_xor(v, 8, 64);
    v += __shfl_xor(v, 16, 64);
    if (sl == 0) sS0[k] = v;
  }
  __syncthreads();

  float S1[8];
#pragma unroll
  for (int k = 0; k < 8; ++k) S1[k] = 0.0f;
#pragma unroll
  for (int pt = 0; pt < PARTS; ++pt) {
    const float* wp = ws_s1 + ((size_t)(bg * PARTS + pt) << 3) * NCH + tid;
#pragma unroll
    for (int k = 0; k < 8; ++k) S1[k] += wp[k * NCH];
  }

  float v[8];
#pragma unroll
  for (int k = 0; k < 8; ++k) {
    float s  = sigma [((g << 3) + k) * NCH + tid];
    float a  = anchor[((g << 3) + k) * NCH + tid];
    float rs = 1.0f / s;
    float S0 = sS0[k];
    float nd = rs * S1[k] - (a * rs) * S0;
    v[k] = nd / (S0 + 1e-9f);
  }

  const int wv = tid >> 6, lane = tid & 63;
#pragma unroll
  for (int k = 0; k < 8; ++k) {
    float s = v[k] * v[k];
    s += __shfl_xor(s, 1, 64);
    s += __shfl_xor(s, 2, 64);
    s += __shfl_xor(s, 4, 64);
    s += __shfl_xor(s, 8, 64);
    s += __shfl_xor(s, 16, 64);
    s += __shfl_xor(s, 32, 64);
    if (lane == 0) red[(wv << 3) + k] = s;
  }
  __syncthreads();
  if (tid < 8) {
    float t2 = 0.0f;
#pragma unroll
    for (int w = 0; w < 8; ++w) t2 += red[(w << 3) + tid];
    invn[tid] = 1.0f / fmaxf(sqrtf(t2), 1e-12f);
  }
  __syncthreads();

  float4 o0 = make_float4(v[0] * invn[0], v[1] * invn[1], v[2] * invn[2], v[3] * invn[3]);
  float4 o1 = make_float4(v[4] * invn[4], v[5] * invn[5], v[6] * invn[6], v[7] * invn[7]);
  float* dst = nodes_out + ((size_t)(b * NCH) + tid) * 128 + (g << 3);
  *(float4*)(dst)     = o0;
  *(float4*)(dst + 4) = o1;
}

extern "C" void kernel_launch(void* const* d_in, const int* in_sizes, int n_in,
                              void* d_out, int out_size, void* d_ws, size_t ws_size,
                              hipStream_t stream) {
  const float* x      = (const float*)d_in[0];
  const float* anchor = (const float*)d_in[1];
  const float* sigma  = (const float*)d_in[2];
  float* out = (float*)d_out;
  float* wsf = (float*)d_ws;

  const size_t n_nodes = 524288;           // 8*512*128
  float* soft_out = out + n_nodes;
  float* ws_anc = wsf;                     // 16*512*16 = 131072 floats
  float* ws_s1  = wsf + 131072;            // 128*2*8*512 floats (4 MB)

  gp_prep <<<16,  512, 0, stream>>>(anchor, sigma, ws_anc);
  gp_fused<<<256, 512, 0, stream>>>(x, ws_anc, soft_out, ws_s1);
  gp_final<<<128, 512, 0, stream>>>(anchor, sigma, soft_out, ws_s1, out);
}